// Round 1
// baseline (1574.358 us; speedup 1.0000x reference)
//
#include <hip/hip_runtime.h>
#include <math.h>

#define NN 20000
#define FF 32
#define TT 12
#define HH 64
#define EE 320000
#define OUTD 12
#define CB 313   // ceil(NN/64)

#define GRIDN 640            // persistent grid: 2.5 blocks/CU avg, capacity-guaranteed at 3/CU
#define NGROUP 32
#define GPB (GRIDN / NGROUP) // 20 blocks per barrier group

typedef __attribute__((ext_vector_type(8))) short short8;
typedef __attribute__((ext_vector_type(4))) float floatx4;

__device__ __forceinline__ float sigmoidf_(float x) { return 1.f / (1.f + expf(-x)); }

__device__ __forceinline__ unsigned short bf16rne(float f) {
    union { float f; unsigned u; } v; v.f = f;
    unsigned u = v.u;
    u += 0x7fffu + ((u >> 16) & 1u);
    return (unsigned short)(u >> 16);
}
__device__ __forceinline__ float lof(unsigned v) {
    union { unsigned u; float f; } x; x.u = v << 16; return x.f;
}
__device__ __forceinline__ float hif(unsigned v) {
    union { unsigned u; float f; } x; x.u = v & 0xffff0000u; return x.f;
}
__device__ __forceinline__ unsigned packbf(float a, float b) {
    return (unsigned)bf16rne(a) | ((unsigned)bf16rne(b) << 16);
}

#define MFMA(a, b, c) __builtin_amdgcn_mfma_f32_16x16x32_bf16((a), (b), (c), 0, 0, 0)

// ---------------- preprocessing ----------------

__global__ void deg_init_kernel(float* deg) {
    int i = blockIdx.x * 256 + threadIdx.x;
    if (i < NN) deg[i] = 1.0f;
}

__global__ void edge_accum_kernel(const int* ei, const float* ea, float* deg, int* cnt) {
    int e = blockIdx.x * 256 + threadIdx.x;
    if (e >= EE) return;
    int d = ei[EE + e];
    float w = ea[e * 2 + 1];
    atomicAdd(&deg[d], w);
    atomicAdd(&cnt[d], 1);
}

__global__ void dinv_kernel(const float* deg, float* dinv) {
    int i = blockIdx.x * 256 + threadIdx.x;
    if (i < NN) dinv[i] = rsqrtf(deg[i]);
}

__global__ void scan_kernel(const int* cnt, int* rowptr, int* cursor) {
    __shared__ int wsum[16];
    int tid = threadIdx.x;
    int lane = tid & 63, w = tid >> 6;
    int run = 0;
    for (int base = 0; base < NN; base += 1024) {
        int idx = base + tid;
        int c = (idx < NN) ? cnt[idx] : 0;
        int v = c;
        #pragma unroll
        for (int off = 1; off < 64; off <<= 1) {
            int t = __shfl_up(v, off, 64);
            if (lane >= off) v += t;
        }
        if (lane == 63) wsum[w] = v;
        __syncthreads();
        if (tid < 16) {
            int x = wsum[tid];
            #pragma unroll
            for (int off = 1; off < 16; off <<= 1) {
                int t = __shfl_up(x, off, 64);
                if (tid >= off) x += t;
            }
            wsum[tid] = x;
        }
        __syncthreads();
        int waveoff = (w > 0) ? wsum[w - 1] : 0;
        int excl = run + waveoff + (v - c);
        if (idx < NN) { rowptr[idx] = excl; cursor[idx] = excl; }
        run += wsum[15];
        __syncthreads();
    }
    if (tid == 0) rowptr[NN] = run;
}

__global__ void fill_kernel(const int* ei, const float* ea, const float* dinv,
                            int* cursor, int* colIdx, float* valArr) {
    int e = blockIdx.x * 256 + threadIdx.x;
    if (e >= EE) return;
    int s = ei[e], d = ei[EE + e];
    float w = ea[e * 2 + 1];
    int pos = atomicAdd(&cursor[d], 1);
    colIdx[pos] = s;
    valArr[pos] = dinv[s] * w * dinv[d];
}

// x (N,F,T) fp32 -> xTs (T,N,F) bf16
__global__ void transpose_kernel(const float* x, unsigned short* xTs) {
    int i = blockIdx.x * 256 + threadIdx.x;
    if (i >= TT * NN * FF) return;
    int f = i & 31;
    int rest = i >> 5;
    int n = rest % NN;
    int t = rest / NN;
    xTs[i] = bf16rne(x[n * (FF * TT) + f * TT + t]);
}

// all 9 weight conversions in one launch; *T variants transpose (K,64)->[64][K]
__global__ void wconv_all(const float* Wg0, const float* Wu0, const float* Wr0, const float* Wc0,
                          const float* Wg1, const float* Wu1, const float* Wr1, const float* Wc1,
                          const float* ipw,
                          short* Wg0T, short* Wu0T, short* Wr0T, short* Wc0T,
                          short* Wg1T, short* Wu1T, short* Wr1T, short* Wc1T, short* ipwB) {
    int i = blockIdx.x * 256 + threadIdx.x;
    if (i < 2048) { int n = i / 32, k = i % 32; Wg0T[i] = (short)bf16rne(Wg0[k * 64 + n]); return; }
    i -= 2048;
    if (i < 10240) { int n = i / 160, k = i % 160; Wu0T[i] = (short)bf16rne(Wu0[k * 64 + n]); return; }
    i -= 10240;
    if (i < 10240) { int n = i / 160, k = i % 160; Wr0T[i] = (short)bf16rne(Wr0[k * 64 + n]); return; }
    i -= 10240;
    if (i < 10240) { int n = i / 160, k = i % 160; Wc0T[i] = (short)bf16rne(Wc0[k * 64 + n]); return; }
    i -= 10240;
    if (i < 4096) { int n = i / 64, k = i % 64; Wg1T[i] = (short)bf16rne(Wg1[k * 64 + n]); return; }
    i -= 4096;
    if (i < 12288) { int n = i / 192, k = i % 192; Wu1T[i] = (short)bf16rne(Wu1[k * 64 + n]); return; }
    i -= 12288;
    if (i < 12288) { int n = i / 192, k = i % 192; Wr1T[i] = (short)bf16rne(Wr1[k * 64 + n]); return; }
    i -= 12288;
    if (i < 12288) { int n = i / 192, k = i % 192; Wc1T[i] = (short)bf16rne(Wc1[k * 64 + n]); return; }
    i -= 12288;
    if (i < 12288) { ipwB[i] = (short)bf16rne(ipw[i]); }
}

// fold output projections
__global__ void fold_out(const float* opw, const float* opb, const float* ow, const float* ob,
                         float* OW2, float* ob2) {
    int i = blockIdx.x * 256 + threadIdx.x;
    if (i < 64 * OUTD) {
        int k = i / OUTD, d = i - k * OUTD;
        float acc = 0.f;
        for (int j = 0; j < 64; ++j) acc += opw[j * 64 + k] * ow[j * OUTD + d];
        OW2[i] = acc;
    } else if (i < 64 * OUTD + OUTD) {
        int d = i - 64 * OUTD;
        float acc = ob[d];
        for (int j = 0; j < 64; ++j) acc += opb[j] * ow[j * OUTD + d];
        ob2[d] = acc;
    }
}

// bf16 aggregation over x planes: 16 lanes/node, 2 features per lane (standalone: full occupancy)
__global__ void gather_raw32(const unsigned short* __restrict__ xTs, const float* __restrict__ dinv,
                             const int* __restrict__ rowptr, const int* __restrict__ colIdx,
                             const float* __restrict__ valArr, unsigned short* __restrict__ aggxs) {
    const unsigned* src = (const unsigned*)(xTs + (size_t)blockIdx.y * NN * 32);
    unsigned* dst = (unsigned*)(aggxs + (size_t)blockIdx.y * NN * 32);
    int node = blockIdx.x * 16 + (threadIdx.x >> 4);
    int l2 = threadIdx.x & 15;
    float di = dinv[node];
    float dd = di * di;
    unsigned v = src[node * 16 + l2];
    float a0 = dd * lof(v), a1 = dd * hif(v);
    int s = rowptr[node], e = rowptr[node + 1];
    int j = s;
    for (; j + 3 < e; j += 4) {
        int c0 = colIdx[j], c1 = colIdx[j + 1], c2 = colIdx[j + 2], c3 = colIdx[j + 3];
        float w0 = valArr[j], w1 = valArr[j + 1], w2 = valArr[j + 2], w3 = valArr[j + 3];
        unsigned v0 = src[c0 * 16 + l2], v1 = src[c1 * 16 + l2];
        unsigned v2 = src[c2 * 16 + l2], v3 = src[c3 * 16 + l2];
        a0 += w0 * lof(v0) + w1 * lof(v1) + w2 * lof(v2) + w3 * lof(v3);
        a1 += w0 * hif(v0) + w1 * hif(v1) + w2 * hif(v2) + w3 * hif(v3);
    }
    for (; j < e; ++j) {
        unsigned vv = src[colIdx[j] * 16 + l2];
        float w = valArr[j];
        a0 += w * lof(vv); a1 += w * hif(vv);
    }
    dst[node * 16 + l2] = packbf(a0, a1);
}

// g0all = sigmoid(aggx @ Wg0 + bg0) -> bf16, rows = T*N, K=32 (standalone)
__launch_bounds__(256, 4)
__global__ void mfma_g0(const unsigned short* __restrict__ aggxs, const short* __restrict__ Wg0T,
                        const float* __restrict__ bg0, unsigned short* __restrict__ g0s) {
    int tid = threadIdx.x;
    int wv = tid >> 6, lane = tid & 63;
    int quad = lane >> 4, ln = lane & 15;
    int m0 = blockIdx.x * 64 + wv * 16;
    short8 af = *reinterpret_cast<const short8*>(aggxs + (size_t)(m0 + ln) * 32 + quad * 8);
    floatx4 z = {0.f, 0.f, 0.f, 0.f};
    floatx4 acc[4] = {z, z, z, z};
    #pragma unroll
    for (int ct = 0; ct < 4; ++ct) {
        short8 bf = *reinterpret_cast<const short8*>(Wg0T + (size_t)(ct * 16 + ln) * 32 + quad * 8);
        acc[ct] = MFMA(af, bf, acc[ct]);
    }
    #pragma unroll
    for (int ct = 0; ct < 4; ++ct) {
        int col = ct * 16 + ln;
        float bb = bg0[col];
        #pragma unroll
        for (int r = 0; r < 4; ++r) {
            int row = m0 + quad * 4 + r;
            g0s[(size_t)row * 64 + col] = bf16rne(sigmoidf_(acc[ct][r] + bb));
        }
    }
}

// ---------------- grid-wide barrier (tree arrival, agent-scope) ----------------
// Monotonic epochs; c1: 32 group counters (padded to separate cachelines); c2: release counter.
__device__ __forceinline__ void gridbar(unsigned* c1, unsigned* c2, unsigned ep) {
    __syncthreads();                 // all waves done; compiler drains vmem before s_barrier
    if (threadIdx.x == 0) {
        __threadfence();             // agent-scope release: write back this XCD's L2
        unsigned g = (unsigned)blockIdx.x & (NGROUP - 1u);
        unsigned old = atomicAdd(&c1[g * 32], 1u);          // agent-scope atomic
        if (old + 1u == ep * GPB) atomicAdd(c2, 1u);        // last in group escalates
        unsigned target = ep * NGROUP;
        long guard = 0;
        while (__hip_atomic_load(c2, __ATOMIC_RELAXED, __HIP_MEMORY_SCOPE_AGENT) < target) {
            __builtin_amdgcn_s_sleep(2);
            if (++guard > 200000000L) break;   // safety: fail loud (wrong result) instead of hang
        }
        __threadfence();             // agent-scope acquire: invalidate stale lines
    }
    __syncthreads();
}

// ---------------- cell bodies ----------------
// A[m=lane&15][k=quad*8+j]; B^T[n=lane&15][k=quad*8+j]; C/D: col=lane&15, row=quad*4+reg.

__device__ __forceinline__ void cell0_body(
    int m0, short* T,
    const unsigned short* __restrict__ xt, const unsigned short* __restrict__ g0,
    const float* __restrict__ h0f, const unsigned short* __restrict__ h0s,
    const short* __restrict__ Wu0T, const short* __restrict__ Wr0T,
    const short* __restrict__ Wc0T, const short* __restrict__ Wg1T,
    const float* __restrict__ bu0, const float* __restrict__ br0,
    const float* __restrict__ bc0,
    float* __restrict__ h0nf, unsigned short* __restrict__ h0ns,
    unsigned short* __restrict__ y0s) {
    int lane = threadIdx.x & 63;
    int quad = lane >> 4, ln = lane & 15;
    int arow = m0 + ln; if (arow > NN - 1) arow = NN - 1;

    short8 af[5];
    af[0] = *reinterpret_cast<const short8*>(xt + (size_t)arow * 32 + quad * 8);
    af[1] = *reinterpret_cast<const short8*>(g0 + (size_t)arow * 64 + quad * 8);
    af[2] = *reinterpret_cast<const short8*>(g0 + (size_t)arow * 64 + 32 + quad * 8);
    af[3] = *reinterpret_cast<const short8*>(h0s + (size_t)arow * 64 + quad * 8);
    af[4] = *reinterpret_cast<const short8*>(h0s + (size_t)arow * 64 + 32 + quad * 8);

    floatx4 z = {0.f, 0.f, 0.f, 0.f};
    floatx4 aU[4] = {z, z, z, z};
    floatx4 aR[4] = {z, z, z, z};
    #pragma unroll
    for (int ct = 0; ct < 4; ++ct) {
        const short* bu = Wu0T + (size_t)(ct * 16 + ln) * 160;
        const short* br = Wr0T + (size_t)(ct * 16 + ln) * 160;
        #pragma unroll
        for (int kc = 0; kc < 5; ++kc) {
            int ko = kc * 32 + quad * 8;
            aU[ct] = MFMA(af[kc], *reinterpret_cast<const short8*>(bu + ko), aU[ct]);
            aR[ct] = MFMA(af[kc], *reinterpret_cast<const short8*>(br + ko), aR[ct]);
        }
    }
    float uu[4][4];
    #pragma unroll
    for (int ct = 0; ct < 4; ++ct) {
        int col = ct * 16 + ln;
        float bU = bu0[col], bR = br0[col];
        #pragma unroll
        for (int r = 0; r < 4; ++r) {
            int grow = m0 + quad * 4 + r;
            bool ok = grow < NN;
            uu[ct][r] = sigmoidf_(aU[ct][r] + bU);
            float hv = ok ? h0f[(size_t)grow * 64 + col] : 0.f;
            float rh = sigmoidf_(aR[ct][r] + bR) * hv;
            T[(quad * 4 + r) * 72 + col] = (short)bf16rne(rh);
        }
    }
    __threadfence_block();

    short8 ar0 = *reinterpret_cast<const short8*>(T + ln * 72 + quad * 8);
    short8 ar1 = *reinterpret_cast<const short8*>(T + ln * 72 + 32 + quad * 8);
    floatx4 aC[4] = {z, z, z, z};
    #pragma unroll
    for (int ct = 0; ct < 4; ++ct) {
        const short* bc = Wc0T + (size_t)(ct * 16 + ln) * 160;
        #pragma unroll
        for (int kc = 0; kc < 3; ++kc)
            aC[ct] = MFMA(af[kc], *reinterpret_cast<const short8*>(bc + kc * 32 + quad * 8), aC[ct]);
        aC[ct] = MFMA(ar0, *reinterpret_cast<const short8*>(bc + 96 + quad * 8), aC[ct]);
        aC[ct] = MFMA(ar1, *reinterpret_cast<const short8*>(bc + 128 + quad * 8), aC[ct]);
    }
    __threadfence_block();
    #pragma unroll
    for (int ct = 0; ct < 4; ++ct) {
        int col = ct * 16 + ln;
        float bC = bc0[col];
        #pragma unroll
        for (int r = 0; r < 4; ++r) {
            int grow = m0 + quad * 4 + r;
            bool ok = grow < NN;
            float hv = ok ? h0f[(size_t)grow * 64 + col] : 0.f;
            float cv = tanhf(aC[ct][r] + bC);
            float hn = uu[ct][r] * hv + (1.f - uu[ct][r]) * cv;
            unsigned short hb = bf16rne(hn);
            if (ok) {
                h0nf[(size_t)grow * 64 + col] = hn;
                h0ns[(size_t)grow * 64 + col] = hb;
            }
            T[(quad * 4 + r) * 72 + col] = (short)hb;
        }
    }
    __threadfence_block();

    short8 ah0 = *reinterpret_cast<const short8*>(T + ln * 72 + quad * 8);
    short8 ah1 = *reinterpret_cast<const short8*>(T + ln * 72 + 32 + quad * 8);
    floatx4 aY[4] = {z, z, z, z};
    #pragma unroll
    for (int ct = 0; ct < 4; ++ct) {
        const short* bg = Wg1T + (size_t)(ct * 16 + ln) * 64;
        aY[ct] = MFMA(ah0, *reinterpret_cast<const short8*>(bg + quad * 8), aY[ct]);
        aY[ct] = MFMA(ah1, *reinterpret_cast<const short8*>(bg + 32 + quad * 8), aY[ct]);
    }
    #pragma unroll
    for (int ct = 0; ct < 4; ++ct) {
        int col = ct * 16 + ln;
        #pragma unroll
        for (int r = 0; r < 4; ++r) {
            int grow = m0 + quad * 4 + r;
            if (grow < NN) y0s[(size_t)grow * 64 + col] = bf16rne(aY[ct][r]);
        }
    }
}

// cell1 with INTEGRATED per-tile gather of g1 (replaces the separate gather_g1 kernel):
// the wave gathers g1 = sigmoid(Ahat*y0 + bg1) for its own 16 rows into T, then proceeds.
__device__ __forceinline__ void cell1x_body(
    int m0, short* T,
    const unsigned short* __restrict__ h0s,
    const float* __restrict__ h1f, const unsigned short* __restrict__ h1s,
    const unsigned short* __restrict__ y0s,
    const float* __restrict__ dinv, const int* __restrict__ rowptr,
    const int* __restrict__ colIdx, const float* __restrict__ valArr,
    const float* __restrict__ bg1,
    const short* __restrict__ Wu1T, const short* __restrict__ Wr1T,
    const short* __restrict__ Wc1T,
    const float* __restrict__ bu1, const float* __restrict__ br1,
    const float* __restrict__ bc1,
    float* __restrict__ h1nf, unsigned short* __restrict__ h1ns) {
    int lane = threadIdx.x & 63;
    int quad = lane >> 4, ln = lane & 15;

    // ---- gather g1 for rows m0..m0+15 into T (2 nodes in parallel per round, 8 rounds) ----
    {
        const unsigned* yp = (const unsigned*)y0s;
        unsigned* Tw = (unsigned*)T;
        int half = lane >> 5, l2 = lane & 31;
        #pragma unroll
        for (int rr = 0; rr < 8; ++rr) {
            int r = rr * 2 + half;
            int node = m0 + r; if (node > NN - 1) node = NN - 1;
            float di = dinv[node];
            float dd = di * di;
            unsigned v = yp[(size_t)node * 32 + l2];
            float a0 = dd * lof(v), a1 = dd * hif(v);
            int s = rowptr[node], e = rowptr[node + 1];
            int j = s;
            for (; j + 3 < e; j += 4) {
                int c0 = colIdx[j], c1 = colIdx[j + 1], c2 = colIdx[j + 2], c3 = colIdx[j + 3];
                float w0 = valArr[j], w1 = valArr[j + 1], w2 = valArr[j + 2], w3 = valArr[j + 3];
                unsigned v0 = yp[(size_t)c0 * 32 + l2], v1 = yp[(size_t)c1 * 32 + l2];
                unsigned v2 = yp[(size_t)c2 * 32 + l2], v3 = yp[(size_t)c3 * 32 + l2];
                a0 += w0 * lof(v0) + w1 * lof(v1) + w2 * lof(v2) + w3 * lof(v3);
                a1 += w0 * hif(v0) + w1 * hif(v1) + w2 * hif(v2) + w3 * hif(v3);
            }
            for (; j < e; ++j) {
                unsigned vv = yp[(size_t)colIdx[j] * 32 + l2];
                float w = valArr[j];
                a0 += w * lof(vv); a1 += w * hif(vv);
            }
            float g0v = sigmoidf_(a0 + bg1[2 * l2]);
            float g1v = sigmoidf_(a1 + bg1[2 * l2 + 1]);
            Tw[r * 36 + l2] = packbf(g0v, g1v);   // T row stride = 72 shorts = 36 dwords
        }
    }
    __threadfence_block();

    int arow = m0 + ln; if (arow > NN - 1) arow = NN - 1;
    short8 af[6];
    af[0] = *reinterpret_cast<const short8*>(h0s + (size_t)arow * 64 + quad * 8);
    af[1] = *reinterpret_cast<const short8*>(h0s + (size_t)arow * 64 + 32 + quad * 8);
    af[2] = *reinterpret_cast<const short8*>(T + ln * 72 + quad * 8);        // g1 from LDS
    af[3] = *reinterpret_cast<const short8*>(T + ln * 72 + 32 + quad * 8);
    af[4] = *reinterpret_cast<const short8*>(h1s + (size_t)arow * 64 + quad * 8);
    af[5] = *reinterpret_cast<const short8*>(h1s + (size_t)arow * 64 + 32 + quad * 8);

    floatx4 z = {0.f, 0.f, 0.f, 0.f};
    floatx4 aU[4] = {z, z, z, z};
    floatx4 aR[4] = {z, z, z, z};
    #pragma unroll
    for (int ct = 0; ct < 4; ++ct) {
        const short* bu = Wu1T + (size_t)(ct * 16 + ln) * 192;
        const short* br = Wr1T + (size_t)(ct * 16 + ln) * 192;
        #pragma unroll
        for (int kc = 0; kc < 6; ++kc) {
            int ko = kc * 32 + quad * 8;
            aU[ct] = MFMA(af[kc], *reinterpret_cast<const short8*>(bu + ko), aU[ct]);
            aR[ct] = MFMA(af[kc], *reinterpret_cast<const short8*>(br + ko), aR[ct]);
        }
    }
    float uu[4][4];
    #pragma unroll
    for (int ct = 0; ct < 4; ++ct) {
        int col = ct * 16 + ln;
        float bU = bu1[col], bR = br1[col];
        #pragma unroll
        for (int r = 0; r < 4; ++r) {
            int grow = m0 + quad * 4 + r;
            bool ok = grow < NN;
            uu[ct][r] = sigmoidf_(aU[ct][r] + bU);
            float hv = ok ? h1f[(size_t)grow * 64 + col] : 0.f;
            float rh = sigmoidf_(aR[ct][r] + bR) * hv;
            T[(quad * 4 + r) * 72 + col] = (short)bf16rne(rh);
        }
    }
    __threadfence_block();

    short8 ar0 = *reinterpret_cast<const short8*>(T + ln * 72 + quad * 8);
    short8 ar1 = *reinterpret_cast<const short8*>(T + ln * 72 + 32 + quad * 8);
    floatx4 aC[4] = {z, z, z, z};
    #pragma unroll
    for (int ct = 0; ct < 4; ++ct) {
        const short* bc = Wc1T + (size_t)(ct * 16 + ln) * 192;
        #pragma unroll
        for (int kc = 0; kc < 4; ++kc)
            aC[ct] = MFMA(af[kc], *reinterpret_cast<const short8*>(bc + kc * 32 + quad * 8), aC[ct]);
        aC[ct] = MFMA(ar0, *reinterpret_cast<const short8*>(bc + 128 + quad * 8), aC[ct]);
        aC[ct] = MFMA(ar1, *reinterpret_cast<const short8*>(bc + 160 + quad * 8), aC[ct]);
    }
    #pragma unroll
    for (int ct = 0; ct < 4; ++ct) {
        int col = ct * 16 + ln;
        float bC = bc1[col];
        #pragma unroll
        for (int r = 0; r < 4; ++r) {
            int grow = m0 + quad * 4 + r;
            if (grow >= NN) continue;
            float hv = h1f[(size_t)grow * 64 + col];
            float cv = tanhf(aC[ct][r] + bC);
            float hn = uu[ct][r] * hv + (1.f - uu[ct][r]) * cv;
            h1nf[(size_t)grow * 64 + col] = hn;
            h1ns[(size_t)grow * 64 + col] = bf16rne(hn);
        }
    }
}

// ---------------- persistent time-loop kernel ----------------

struct LoopArgs {
    const unsigned short* xTs;
    const unsigned short* g0s;
    const float* dinv;
    const int* rowptr;
    const int* colIdx;
    const float* valArr;
    const short* Wu0T; const short* Wr0T; const short* Wc0T; const short* Wg1T;
    const float* bu0; const float* br0; const float* bc0;
    const short* Wu1T; const short* Wr1T; const short* Wc1T;
    const float* bu1; const float* br1; const float* bc1; const float* bg1;
    float* h0f0; float* h0f1;
    unsigned short* h0s0; unsigned short* h0s1;
    float* h1f0; float* h1f1;
    const unsigned short* h1s0;
    unsigned short* hseqs;
    unsigned short* y0sA; unsigned short* y0sB;
    unsigned* bar1; unsigned* bar2;
};

// One phase per timestep: blocks [0,CB) do (gather g1 + cell1)(t); blocks [CB,2CB) do cell0(t+1).
// Grid barrier between phases. __launch_bounds__(256,3) guarantees >=3 blocks/CU residency
// (768 >= GRIDN=640), so the capacity-barrier pattern is safe.
__launch_bounds__(256, 3)
__global__ void tgcn_loop(LoopArgs A) {
    __shared__ short lds[4 * 16 * 72];
    int wv = threadIdx.x >> 6;
    short* T = lds + wv * (16 * 72);
    unsigned ep = 0;

    // boot: cell0(t=0), reads zeroed h0f1/h0s1, writes h0f0/h0s0/y0sA
    for (int vb = blockIdx.x; vb < CB; vb += GRIDN)
        cell0_body(vb * 64 + wv * 16, T, A.xTs, A.g0s, A.h0f1, A.h0s1,
                   A.Wu0T, A.Wr0T, A.Wc0T, A.Wg1T, A.bu0, A.br0, A.bc0,
                   A.h0f0, A.h0s0, A.y0sA);
    gridbar(A.bar1, A.bar2, ++ep);

    for (int t = 0; t < TT; ++t) {
        const int tp = t & 1;
        const unsigned short* h0s_cur = tp ? A.h0s1 : A.h0s0;
        const float* h0f_cur = tp ? A.h0f1 : A.h0f0;
        float* h0f_nxt = tp ? A.h0f0 : A.h0f1;
        unsigned short* h0s_nxt = tp ? A.h0s0 : A.h0s1;
        const unsigned short* y0_cur = tp ? A.y0sB : A.y0sA;
        unsigned short* y0_nxt = tp ? A.y0sA : A.y0sB;
        const float* h1f_in = tp ? A.h1f0 : A.h1f1;
        float* h1f_out = tp ? A.h1f1 : A.h1f0;
        const unsigned short* h1s_in =
            (t == 0) ? A.h1s0 : (const unsigned short*)(A.hseqs + (size_t)(t - 1) * NN * HH);
        unsigned short* h1s_out = A.hseqs + (size_t)t * NN * HH;

        int nstep = (t < TT - 1) ? 2 * CB : CB;
        for (int vb = blockIdx.x; vb < nstep; vb += GRIDN) {
            if (vb < CB) {
                cell1x_body(vb * 64 + wv * 16, T,
                            h0s_cur, h1f_in, h1s_in, y0_cur,
                            A.dinv, A.rowptr, A.colIdx, A.valArr, A.bg1,
                            A.Wu1T, A.Wr1T, A.Wc1T, A.bu1, A.br1, A.bc1,
                            h1f_out, h1s_out);
            } else {
                cell0_body((vb - CB) * 64 + wv * 16, T,
                           A.xTs + (size_t)(t + 1) * NN * FF, A.g0s + (size_t)(t + 1) * NN * HH,
                           h0f_cur, h0s_cur,
                           A.Wu0T, A.Wr0T, A.Wc0T, A.Wg1T, A.bu0, A.br0, A.bc0,
                           h0f_nxt, h0s_nxt, y0_nxt);
            }
        }
        gridbar(A.bar1, A.bar2, ++ep);
    }
}

// ---------------- fused qkv + attention: one wave per node ----------------
__launch_bounds__(256, 5)
__global__ void attn_fused(const unsigned short* __restrict__ hseqs,
                           const short* __restrict__ ipwB, const float* __restrict__ ipb,
                           const float* __restrict__ OW2, const float* __restrict__ ob2,
                           float* __restrict__ out) {
    __shared__ unsigned short qtile[4][16 * 200];
    __shared__ float fbuf[4][64];
    __shared__ float wbuf[4][32];
    int wv = threadIdx.x >> 6, lane = threadIdx.x & 63;
    int node = blockIdx.x * 4 + wv;
    int quad = lane >> 4, ln = lane & 15;
    unsigned short* q = qtile[wv];
    float* sob = fbuf[wv];
    float* W = wbuf[wv];

    short8 zero8 = {0, 0, 0, 0, 0, 0, 0, 0};
    short8 af0 = zero8, af1 = zero8;
    if (ln < TT) {
        const unsigned short* hp = hseqs + ((size_t)ln * NN + node) * 64;
        af0 = *reinterpret_cast<const short8*>(hp + quad * 8);
        af1 = *reinterpret_cast<const short8*>(hp + 32 + quad * 8);
    }
    floatx4 z = {0.f, 0.f, 0.f, 0.f};
    #pragma unroll
    for (int ct = 0; ct < 12; ++ct) {
        const short* br = ipwB + (size_t)(ct * 16 + ln) * 64;
        floatx4 acc = MFMA(af0, *reinterpret_cast<const short8*>(br + quad * 8), z);
        acc = MFMA(af1, *reinterpret_cast<const short8*>(br + 32 + quad * 8), acc);
        int col = ct * 16 + ln;
        float bb = ipb[col];
        #pragma unroll
        for (int r = 0; r < 4; ++r)
            q[(quad * 4 + r) * 200 + col] = bf16rne(acc[r] + bb);
    }
    __threadfence_block();

    floatx4 sc[2];
    #pragma unroll
    for (int h = 0; h < 2; ++h) {
        short8 aQ = *reinterpret_cast<const short8*>(q + ln * 200 + h * 32 + quad * 8);
        short8 bK = *reinterpret_cast<const short8*>(q + ln * 200 + 64 + h * 32 + quad * 8);
        sc[h] = MFMA(aQ, bK, z);
    }
    const float scl = 0.17677669529663687f;
    bool colok = ln < 12;
    #pragma unroll
    for (int h = 0; h < 2; ++h) {
        float p[4];
        #pragma unroll
        for (int r = 0; r < 4; ++r) {
            float v = colok ? sc[h][r] * scl : -1e30f;
            float m = v;
            m = fmaxf(m, __shfl_xor(m, 1, 64));
            m = fmaxf(m, __shfl_xor(m, 2, 64));
            m = fmaxf(m, __shfl_xor(m, 4, 64));
            m = fmaxf(m, __shfl_xor(m, 8, 64));
            float e = colok ? expf(v - m) : 0.f;
            float s = e;
            s += __shfl_xor(s, 1, 64);
            s += __shfl_xor(s, 2, 64);
            s += __shfl_xor(s, 4, 64);
            s += __shfl_xor(s, 8, 64);
            p[r] = e / s;
        }
        float ts = (quad < 3) ? (p[0] + p[1] + p[2] + p[3]) : 0.f;
        ts += __shfl_xor(ts, 16, 64);
        ts += __shfl_xor(ts, 32, 64);
        if (quad == 0) W[h * 16 + ln] = ts * (1.f / 12.f);
    }
    __threadfence_block();

    {
        int d = lane, hd = d >> 5, dd = d & 31;
        float acc = 0.f;
        #pragma unroll
        for (int ts = 0; ts < 12; ++ts)
            acc += W[hd * 16 + ts] * lof((unsigned)q[ts * 200 + 128 + hd * 32 + dd]);
        sob[d] = acc;
    }
    __threadfence_block();

    if (lane < OUTD) {
        float acc = ob2[lane];
        #pragma unroll
        for (int k = 0; k < 64; ++k) acc += sob[k] * OW2[k * OUTD + lane];
        out[(size_t)node * OUTD + lane] = acc;
    }
}

// ---------------- launcher ----------------

extern "C" void kernel_launch(void* const* d_in, const int* in_sizes, int n_in,
                              void* d_out, int out_size, void* d_ws, size_t ws_size,
                              hipStream_t stream) {
    const float* x   = (const float*)d_in[0];
    const int*   ei  = (const int*)d_in[1];
    const float* ea  = (const float*)d_in[2];
    const float* Wg0 = (const float*)d_in[3];
    const float* bg0 = (const float*)d_in[4];
    const float* Wu0 = (const float*)d_in[5];
    const float* bu0 = (const float*)d_in[6];
    const float* Wr0 = (const float*)d_in[7];
    const float* br0 = (const float*)d_in[8];
    const float* Wc0 = (const float*)d_in[9];
    const float* bc0 = (const float*)d_in[10];
    const float* Wg1 = (const float*)d_in[11];
    const float* bg1 = (const float*)d_in[12];
    const float* Wu1 = (const float*)d_in[13];
    const float* bu1 = (const float*)d_in[14];
    const float* Wr1 = (const float*)d_in[15];
    const float* br1 = (const float*)d_in[16];
    const float* Wc1 = (const float*)d_in[17];
    const float* bc1 = (const float*)d_in[18];
    const float* ipw = (const float*)d_in[19];
    const float* ipb = (const float*)d_in[20];
    const float* opw = (const float*)d_in[21];
    const float* opb = (const float*)d_in[22];
    const float* ow  = (const float*)d_in[23];
    const float* ob  = (const float*)d_in[24];
    float* out = (float*)d_out;

    char* p = (char*)d_ws;
    auto alloc = [&](size_t bytes) { char* r = p; p += (bytes + 255) & ~(size_t)255; return (void*)r; };
    unsigned short* hseqs = (unsigned short*)alloc((size_t)TT * NN * HH * 2);
    unsigned short* h1s0  = (unsigned short*)alloc((size_t)NN * HH * 2);
    short* Wg0T = (short*)alloc((size_t)64 * 32 * 2);
    short* Wu0T = (short*)alloc((size_t)64 * 160 * 2);
    short* Wr0T = (short*)alloc((size_t)64 * 160 * 2);
    short* Wc0T = (short*)alloc((size_t)64 * 160 * 2);
    short* Wg1T = (short*)alloc((size_t)64 * 64 * 2);
    short* Wu1T = (short*)alloc((size_t)64 * 192 * 2);
    short* Wr1T = (short*)alloc((size_t)64 * 192 * 2);
    short* Wc1T = (short*)alloc((size_t)64 * 192 * 2);
    short* ipwB = (short*)alloc((size_t)192 * 64 * 2);
    float* OW2  = (float*)alloc((size_t)64 * OUTD * 4);
    float* ob2  = (float*)alloc((size_t)OUTD * 4);
    float* dinv   = (float*)alloc((size_t)NN * 4);
    int*   rowptr = (int*)  alloc((size_t)(NN + 1) * 4);
    int*   colIdx = (int*)  alloc((size_t)EE * 4);
    float* valArr = (float*)alloc((size_t)EE * 4);
    unsigned short* xTs   = (unsigned short*)alloc((size_t)TT * NN * FF * 2);
    unsigned short* aggxs = (unsigned short*)alloc((size_t)TT * NN * FF * 2);
    unsigned short* g0s   = (unsigned short*)alloc((size_t)TT * NN * HH * 2);
    float* deg    = (float*)alloc((size_t)NN * 4);
    int*   cnt    = (int*)  alloc((size_t)NN * 4);
    int*   cursor = (int*)  alloc((size_t)NN * 4);
    unsigned short* y0sA = (unsigned short*)alloc((size_t)NN * HH * 2);
    unsigned short* y0sB = (unsigned short*)alloc((size_t)NN * HH * 2);
    float* h0f0 = (float*)alloc((size_t)NN * HH * 4);
    float* h0f1 = (float*)alloc((size_t)NN * HH * 4);
    float* h1f0 = (float*)alloc((size_t)NN * HH * 4);
    float* h1f1 = (float*)alloc((size_t)NN * HH * 4);
    unsigned short* h0s0 = (unsigned short*)alloc((size_t)NN * HH * 2);
    unsigned short* h0s1 = (unsigned short*)alloc((size_t)NN * HH * 2);
    unsigned* bars = (unsigned*)alloc(4096 + 256);   // bar1: 32 padded groups; bar2 at +1024
    (void)ws_size;

    hipMemsetAsync(cnt, 0, (size_t)NN * 4, stream);
    hipMemsetAsync(h0f1, 0, (size_t)NN * HH * 4, stream);
    hipMemsetAsync(h1f1, 0, (size_t)NN * HH * 4, stream);
    hipMemsetAsync(h0s1, 0, (size_t)NN * HH * 2, stream);
    hipMemsetAsync(h1s0, 0, (size_t)NN * HH * 2, stream);
    hipMemsetAsync(bars, 0, 4096 + 256, stream);
    deg_init_kernel<<<(NN + 255) / 256, 256, 0, stream>>>(deg);
    edge_accum_kernel<<<(EE + 255) / 256, 256, 0, stream>>>(ei, ea, deg, cnt);
    dinv_kernel<<<(NN + 255) / 256, 256, 0, stream>>>(deg, dinv);
    scan_kernel<<<1, 1024, 0, stream>>>(cnt, rowptr, cursor);
    fill_kernel<<<(EE + 255) / 256, 256, 0, stream>>>(ei, ea, dinv, cursor, colIdx, valArr);
    transpose_kernel<<<(TT * NN * FF + 255) / 256, 256, 0, stream>>>(x, xTs);
    wconv_all<<<(86016 + 255) / 256, 256, 0, stream>>>(
        Wg0, Wu0, Wr0, Wc0, Wg1, Wu1, Wr1, Wc1, ipw,
        Wg0T, Wu0T, Wr0T, Wc0T, Wg1T, Wu1T, Wr1T, Wc1T, ipwB);
    fold_out<<<4, 256, 0, stream>>>(opw, opb, ow, ob, OW2, ob2);

    gather_raw32<<<dim3(NN / 16, TT), 256, 0, stream>>>(xTs, dinv, rowptr, colIdx, valArr, aggxs);
    mfma_g0<<<(TT * NN) / 64, 256, 0, stream>>>(aggxs, Wg0T, bg0, g0s);

    LoopArgs A;
    A.xTs = xTs; A.g0s = g0s;
    A.dinv = dinv; A.rowptr = rowptr; A.colIdx = colIdx; A.valArr = valArr;
    A.Wu0T = Wu0T; A.Wr0T = Wr0T; A.Wc0T = Wc0T; A.Wg1T = Wg1T;
    A.bu0 = bu0; A.br0 = br0; A.bc0 = bc0;
    A.Wu1T = Wu1T; A.Wr1T = Wr1T; A.Wc1T = Wc1T;
    A.bu1 = bu1; A.br1 = br1; A.bc1 = bc1; A.bg1 = bg1;
    A.h0f0 = h0f0; A.h0f1 = h0f1; A.h0s0 = h0s0; A.h0s1 = h0s1;
    A.h1f0 = h1f0; A.h1f1 = h1f1; A.h1s0 = h1s0;
    A.hseqs = hseqs; A.y0sA = y0sA; A.y0sB = y0sB;
    A.bar1 = bars; A.bar2 = bars + 1024;

    tgcn_loop<<<GRIDN, 256, 0, stream>>>(A);

    attn_fused<<<NN / 4, 256, 0, stream>>>(hseqs, ipwB, ipb, OW2, ob2, out);
}

// Round 2
// 945.034 us; speedup vs baseline: 1.6659x; 1.6659x over previous
//
#include <hip/hip_runtime.h>
#include <math.h>

#define NN 20000
#define FF 32
#define TT 12
#define HH 64
#define EE 320000
#define OUTD 12
#define CB 313   // ceil(NN/64)

typedef __attribute__((ext_vector_type(8))) short short8;
typedef __attribute__((ext_vector_type(4))) float floatx4;

// ---- fast transcendentals: v_exp_f32 computes 2^x; v_rcp_f32 approx 1/x (~1 ulp) ----
__device__ __forceinline__ float aexp2(float x) {
    float r; asm("v_exp_f32 %0, %1" : "=v"(r) : "v"(x)); return r;
}
__device__ __forceinline__ float arcp(float x) {
    float r; asm("v_rcp_f32 %0, %1" : "=v"(r) : "v"(x)); return r;
}
#define LOG2E 1.44269504088896f
// sigmoid(x) = 1/(1+e^-x); e^-x = 2^(-x*log2e). Large |x| saturates via inf/0 correctly.
__device__ __forceinline__ float fsig(float x) { return arcp(1.f + aexp2(-LOG2E * x)); }
// tanh(x) = 1 - 2/(1+e^{2x})
__device__ __forceinline__ float ftanh(float x) {
    return fmaf(-2.f, arcp(1.f + aexp2(2.f * LOG2E * x)), 1.f);
}

__device__ __forceinline__ unsigned short bf16rne(float f) {
    union { float f; unsigned u; } v; v.f = f;
    unsigned u = v.u;
    u += 0x7fffu + ((u >> 16) & 1u);
    return (unsigned short)(u >> 16);
}
__device__ __forceinline__ float lof(unsigned v) {
    union { unsigned u; float f; } x; x.u = v << 16; return x.f;
}
__device__ __forceinline__ float hif(unsigned v) {
    union { unsigned u; float f; } x; x.u = v & 0xffff0000u; return x.f;
}
__device__ __forceinline__ unsigned packbf(float a, float b) {
    return (unsigned)bf16rne(a) | ((unsigned)bf16rne(b) << 16);
}

#define MFMA(a, b, c) __builtin_amdgcn_mfma_f32_16x16x32_bf16((a), (b), (c), 0, 0, 0)

// ---------------- preprocessing ----------------

// one kernel replaces: deg_init + 4 state memsets + cnt memset
__global__ void init_all(float* deg, int* cnt, float* h0f1, float* h1f1,
                         unsigned* h0s1u, unsigned* h1s0u) {
    int i = blockIdx.x * 256 + threadIdx.x;
    if (i < NN) { deg[i] = 1.0f; cnt[i] = 0; }
    if (i < NN * HH) { h0f1[i] = 0.f; h1f1[i] = 0.f; }
    if (i < NN * HH / 2) { h0s1u[i] = 0u; h1s0u[i] = 0u; }
}

__global__ void edge_accum_kernel(const int* ei, const float* ea, float* deg, int* cnt) {
    int e = blockIdx.x * 256 + threadIdx.x;
    if (e >= EE) return;
    int d = ei[EE + e];
    float w = ea[e * 2 + 1];
    atomicAdd(&deg[d], w);
    atomicAdd(&cnt[d], 1);
}

// block 0: serial scan of cnt -> rowptr/cursor; blocks 1..: dinv = rsqrt(deg)
__global__ void scan_dinv(const int* cnt, int* rowptr, int* cursor,
                          const float* deg, float* dinv) {
    if (blockIdx.x != 0) {
        int i = (blockIdx.x - 1) * 1024 + threadIdx.x;
        if (i < NN) dinv[i] = rsqrtf(deg[i]);
        return;
    }
    __shared__ int wsum[16];
    int tid = threadIdx.x;
    int lane = tid & 63, w = tid >> 6;
    int run = 0;
    for (int base = 0; base < NN; base += 1024) {
        int idx = base + tid;
        int c = (idx < NN) ? cnt[idx] : 0;
        int v = c;
        #pragma unroll
        for (int off = 1; off < 64; off <<= 1) {
            int t = __shfl_up(v, off, 64);
            if (lane >= off) v += t;
        }
        if (lane == 63) wsum[w] = v;
        __syncthreads();
        if (tid < 16) {
            int x = wsum[tid];
            #pragma unroll
            for (int off = 1; off < 16; off <<= 1) {
                int t = __shfl_up(x, off, 64);
                if (tid >= off) x += t;
            }
            wsum[tid] = x;
        }
        __syncthreads();
        int waveoff = (w > 0) ? wsum[w - 1] : 0;
        int excl = run + waveoff + (v - c);
        if (idx < NN) { rowptr[idx] = excl; cursor[idx] = excl; }
        run += wsum[15];
        __syncthreads();
    }
    if (tid == 0) rowptr[NN] = run;
}

// packed CSR payload: {col, bits(norm)} in one 8B load
__global__ void fill_kernel(const int* ei, const float* ea, const float* dinv,
                            int* cursor, int2* colval) {
    int e = blockIdx.x * 256 + threadIdx.x;
    if (e >= EE) return;
    int s = ei[e], d = ei[EE + e];
    float w = ea[e * 2 + 1];
    int pos = atomicAdd(&cursor[d], 1);
    colval[pos] = make_int2(s, __float_as_int(dinv[s] * w * dinv[d]));
}

// fused: transpose (blocks [0,30000)) + weight conversion ([30000,30336)) + fold_out ([30336,30340))
#define TRB 30000
#define WCB 336
__global__ void prep_misc(const float* x, unsigned short* xTs,
                          const float* Wg0, const float* Wu0, const float* Wr0, const float* Wc0,
                          const float* Wg1, const float* Wu1, const float* Wr1, const float* Wc1,
                          const float* ipw,
                          short* Wg0T, short* Wu0T, short* Wr0T, short* Wc0T,
                          short* Wg1T, short* Wu1T, short* Wr1T, short* Wc1T, short* ipwB,
                          const float* opw, const float* opb, const float* ow, const float* ob,
                          float* OW2, float* ob2) {
    int b = blockIdx.x;
    if (b < TRB) {
        int i = b * 256 + threadIdx.x;   // i < TT*NN*FF exactly (7,680,000)
        int f = i & 31;
        int rest = i >> 5;
        int n = rest % NN;
        int t = rest / NN;
        xTs[i] = bf16rne(x[n * (FF * TT) + f * TT + t]);
        return;
    }
    if (b < TRB + WCB) {
        int i = (b - TRB) * 256 + threadIdx.x;
        if (i < 2048) { int n = i / 32, k = i % 32; Wg0T[i] = (short)bf16rne(Wg0[k * 64 + n]); return; }
        i -= 2048;
        if (i < 10240) { int n = i / 160, k = i % 160; Wu0T[i] = (short)bf16rne(Wu0[k * 64 + n]); return; }
        i -= 10240;
        if (i < 10240) { int n = i / 160, k = i % 160; Wr0T[i] = (short)bf16rne(Wr0[k * 64 + n]); return; }
        i -= 10240;
        if (i < 10240) { int n = i / 160, k = i % 160; Wc0T[i] = (short)bf16rne(Wc0[k * 64 + n]); return; }
        i -= 10240;
        if (i < 4096) { int n = i / 64, k = i % 64; Wg1T[i] = (short)bf16rne(Wg1[k * 64 + n]); return; }
        i -= 4096;
        if (i < 12288) { int n = i / 192, k = i % 192; Wu1T[i] = (short)bf16rne(Wu1[k * 64 + n]); return; }
        i -= 12288;
        if (i < 12288) { int n = i / 192, k = i % 192; Wr1T[i] = (short)bf16rne(Wr1[k * 64 + n]); return; }
        i -= 12288;
        if (i < 12288) { int n = i / 192, k = i % 192; Wc1T[i] = (short)bf16rne(Wc1[k * 64 + n]); return; }
        i -= 12288;
        if (i < 12288) { ipwB[i] = (short)bf16rne(ipw[i]); }
        return;
    }
    {
        int i = (b - TRB - WCB) * 256 + threadIdx.x;
        if (i < 64 * OUTD) {
            int k = i / OUTD, d = i - k * OUTD;
            float acc = 0.f;
            for (int j = 0; j < 64; ++j) acc += opw[j * 64 + k] * ow[j * OUTD + d];
            OW2[i] = acc;
        } else if (i < 64 * OUTD + OUTD) {
            int d = i - 64 * OUTD;
            float acc = ob[d];
            for (int j = 0; j < 64; ++j) acc += opb[j] * ow[j * OUTD + d];
            ob2[d] = acc;
        }
    }
}

// bf16 aggregation over x planes: 16 lanes/node, 2 features per lane
__global__ void gather_raw32(const unsigned short* __restrict__ xTs, const float* __restrict__ dinv,
                             const int* __restrict__ rowptr, const int2* __restrict__ colval,
                             unsigned short* __restrict__ aggxs) {
    const unsigned* src = (const unsigned*)(xTs + (size_t)blockIdx.y * NN * 32);
    unsigned* dst = (unsigned*)(aggxs + (size_t)blockIdx.y * NN * 32);
    int node = blockIdx.x * 16 + (threadIdx.x >> 4);
    int l2 = threadIdx.x & 15;
    float di = dinv[node];
    float dd = di * di;
    unsigned v = src[node * 16 + l2];
    float a0 = dd * lof(v), a1 = dd * hif(v);
    int s = rowptr[node], e = rowptr[node + 1];
    int j = s;
    for (; j + 3 < e; j += 4) {
        int2 cv0 = colval[j], cv1 = colval[j + 1], cv2 = colval[j + 2], cv3 = colval[j + 3];
        float w0 = __int_as_float(cv0.y), w1 = __int_as_float(cv1.y);
        float w2 = __int_as_float(cv2.y), w3 = __int_as_float(cv3.y);
        unsigned v0 = src[cv0.x * 16 + l2], v1 = src[cv1.x * 16 + l2];
        unsigned v2 = src[cv2.x * 16 + l2], v3 = src[cv3.x * 16 + l2];
        a0 += w0 * lof(v0) + w1 * lof(v1) + w2 * lof(v2) + w3 * lof(v3);
        a1 += w0 * hif(v0) + w1 * hif(v1) + w2 * hif(v2) + w3 * hif(v3);
    }
    for (; j < e; ++j) {
        int2 cv = colval[j];
        unsigned vv = src[cv.x * 16 + l2];
        float w = __int_as_float(cv.y);
        a0 += w * lof(vv); a1 += w * hif(vv);
    }
    dst[node * 16 + l2] = packbf(a0, a1);
}

// gather y0 (bf16) + sigmoid -> g1 (bf16): 32 lanes/node
__global__ void gather_g1(const unsigned short* __restrict__ y0s, const float* __restrict__ dinv,
                          const int* __restrict__ rowptr, const int2* __restrict__ colval,
                          const float* __restrict__ bg1, unsigned short* __restrict__ g1s) {
    const unsigned* yp = (const unsigned*)y0s;
    int node = blockIdx.x * 8 + (threadIdx.x >> 5);
    int l2 = threadIdx.x & 31;
    float di = dinv[node];
    float dd = di * di;
    unsigned v = yp[node * 32 + l2];
    float a0 = dd * lof(v), a1 = dd * hif(v);
    int s = rowptr[node], e = rowptr[node + 1];
    int j = s;
    for (; j + 3 < e; j += 4) {
        int2 cv0 = colval[j], cv1 = colval[j + 1], cv2 = colval[j + 2], cv3 = colval[j + 3];
        float w0 = __int_as_float(cv0.y), w1 = __int_as_float(cv1.y);
        float w2 = __int_as_float(cv2.y), w3 = __int_as_float(cv3.y);
        unsigned v0 = yp[cv0.x * 32 + l2], v1 = yp[cv1.x * 32 + l2];
        unsigned v2 = yp[cv2.x * 32 + l2], v3 = yp[cv3.x * 32 + l2];
        a0 += w0 * lof(v0) + w1 * lof(v1) + w2 * lof(v2) + w3 * lof(v3);
        a1 += w0 * hif(v0) + w1 * hif(v1) + w2 * hif(v2) + w3 * hif(v3);
    }
    for (; j < e; ++j) {
        int2 cv = colval[j];
        unsigned vv = yp[cv.x * 32 + l2];
        float w = __int_as_float(cv.y);
        a0 += w * lof(vv); a1 += w * hif(vv);
    }
    float g0v = fsig(a0 + bg1[2 * l2]);
    float g1v = fsig(a1 + bg1[2 * l2 + 1]);
    ((unsigned*)g1s)[node * 32 + l2] = packbf(g0v, g1v);
}

// ---------------- MFMA kernels ----------------
// A[m=lane&15][k=quad*8+j]; B^T[n=lane&15][k=quad*8+j]; C/D: col=lane&15, row=quad*4+reg.

__launch_bounds__(256, 4)
__global__ void mfma_g0(const unsigned short* __restrict__ aggxs, const short* __restrict__ Wg0T,
                        const float* __restrict__ bg0, unsigned short* __restrict__ g0s) {
    int tid = threadIdx.x;
    int wv = tid >> 6, lane = tid & 63;
    int quad = lane >> 4, ln = lane & 15;
    int m0 = blockIdx.x * 64 + wv * 16;
    short8 af = *reinterpret_cast<const short8*>(aggxs + (size_t)(m0 + ln) * 32 + quad * 8);
    floatx4 z = {0.f, 0.f, 0.f, 0.f};
    floatx4 acc[4] = {z, z, z, z};
    #pragma unroll
    for (int ct = 0; ct < 4; ++ct) {
        short8 bf = *reinterpret_cast<const short8*>(Wg0T + (size_t)(ct * 16 + ln) * 32 + quad * 8);
        acc[ct] = MFMA(af, bf, acc[ct]);
    }
    #pragma unroll
    for (int ct = 0; ct < 4; ++ct) {
        int col = ct * 16 + ln;
        float bb = bg0[col];
        #pragma unroll
        for (int r = 0; r < 4; ++r) {
            int row = m0 + quad * 4 + r;
            g0s[(size_t)row * 64 + col] = bf16rne(fsig(acc[ct][r] + bb));
        }
    }
}

// ---- cell bodies (per-wave 16-row tile, wave-private LDS slice T) ----

__device__ __forceinline__ void cell0_body(
    int m0, short* T,
    const unsigned short* __restrict__ xt, const unsigned short* __restrict__ g0,
    const float* __restrict__ h0f, const unsigned short* __restrict__ h0s,
    const short* __restrict__ Wu0T, const short* __restrict__ Wr0T,
    const short* __restrict__ Wc0T, const short* __restrict__ Wg1T,
    const float* __restrict__ bu0, const float* __restrict__ br0,
    const float* __restrict__ bc0,
    float* __restrict__ h0nf, unsigned short* __restrict__ h0ns,
    unsigned short* __restrict__ y0s) {
    int lane = threadIdx.x & 63;
    int quad = lane >> 4, ln = lane & 15;
    int arow = m0 + ln; if (arow > NN - 1) arow = NN - 1;

    short8 af[5];
    af[0] = *reinterpret_cast<const short8*>(xt + (size_t)arow * 32 + quad * 8);
    af[1] = *reinterpret_cast<const short8*>(g0 + (size_t)arow * 64 + quad * 8);
    af[2] = *reinterpret_cast<const short8*>(g0 + (size_t)arow * 64 + 32 + quad * 8);
    af[3] = *reinterpret_cast<const short8*>(h0s + (size_t)arow * 64 + quad * 8);
    af[4] = *reinterpret_cast<const short8*>(h0s + (size_t)arow * 64 + 32 + quad * 8);

    floatx4 z = {0.f, 0.f, 0.f, 0.f};
    floatx4 aU[4] = {z, z, z, z};
    floatx4 aR[4] = {z, z, z, z};
    #pragma unroll
    for (int ct = 0; ct < 4; ++ct) {
        const short* bu = Wu0T + (size_t)(ct * 16 + ln) * 160;
        const short* br = Wr0T + (size_t)(ct * 16 + ln) * 160;
        #pragma unroll
        for (int kc = 0; kc < 5; ++kc) {
            int ko = kc * 32 + quad * 8;
            aU[ct] = MFMA(af[kc], *reinterpret_cast<const short8*>(bu + ko), aU[ct]);
            aR[ct] = MFMA(af[kc], *reinterpret_cast<const short8*>(br + ko), aR[ct]);
        }
    }
    float uu[4][4];
    #pragma unroll
    for (int ct = 0; ct < 4; ++ct) {
        int col = ct * 16 + ln;
        float bU = bu0[col], bR = br0[col];
        #pragma unroll
        for (int r = 0; r < 4; ++r) {
            int grow = m0 + quad * 4 + r;
            bool ok = grow < NN;
            uu[ct][r] = fsig(aU[ct][r] + bU);
            float hv = ok ? h0f[(size_t)grow * 64 + col] : 0.f;
            float rh = fsig(aR[ct][r] + bR) * hv;
            T[(quad * 4 + r) * 72 + col] = (short)bf16rne(rh);
        }
    }
    __threadfence_block();

    short8 ar0 = *reinterpret_cast<const short8*>(T + ln * 72 + quad * 8);
    short8 ar1 = *reinterpret_cast<const short8*>(T + ln * 72 + 32 + quad * 8);
    floatx4 aC[4] = {z, z, z, z};
    #pragma unroll
    for (int ct = 0; ct < 4; ++ct) {
        const short* bc = Wc0T + (size_t)(ct * 16 + ln) * 160;
        #pragma unroll
        for (int kc = 0; kc < 3; ++kc)
            aC[ct] = MFMA(af[kc], *reinterpret_cast<const short8*>(bc + kc * 32 + quad * 8), aC[ct]);
        aC[ct] = MFMA(ar0, *reinterpret_cast<const short8*>(bc + 96 + quad * 8), aC[ct]);
        aC[ct] = MFMA(ar1, *reinterpret_cast<const short8*>(bc + 128 + quad * 8), aC[ct]);
    }
    __threadfence_block();
    #pragma unroll
    for (int ct = 0; ct < 4; ++ct) {
        int col = ct * 16 + ln;
        float bC = bc0[col];
        #pragma unroll
        for (int r = 0; r < 4; ++r) {
            int grow = m0 + quad * 4 + r;
            bool ok = grow < NN;
            float hv = ok ? h0f[(size_t)grow * 64 + col] : 0.f;
            float cv = ftanh(aC[ct][r] + bC);
            float hn = uu[ct][r] * hv + (1.f - uu[ct][r]) * cv;
            unsigned short hb = bf16rne(hn);
            if (ok) {
                h0nf[(size_t)grow * 64 + col] = hn;
                h0ns[(size_t)grow * 64 + col] = hb;
            }
            T[(quad * 4 + r) * 72 + col] = (short)hb;
        }
    }
    __threadfence_block();

    short8 ah0 = *reinterpret_cast<const short8*>(T + ln * 72 + quad * 8);
    short8 ah1 = *reinterpret_cast<const short8*>(T + ln * 72 + 32 + quad * 8);
    floatx4 aY[4] = {z, z, z, z};
    #pragma unroll
    for (int ct = 0; ct < 4; ++ct) {
        const short* bg = Wg1T + (size_t)(ct * 16 + ln) * 64;
        aY[ct] = MFMA(ah0, *reinterpret_cast<const short8*>(bg + quad * 8), aY[ct]);
        aY[ct] = MFMA(ah1, *reinterpret_cast<const short8*>(bg + 32 + quad * 8), aY[ct]);
    }
    #pragma unroll
    for (int ct = 0; ct < 4; ++ct) {
        int col = ct * 16 + ln;
        #pragma unroll
        for (int r = 0; r < 4; ++r) {
            int grow = m0 + quad * 4 + r;
            if (grow < NN) y0s[(size_t)grow * 64 + col] = bf16rne(aY[ct][r]);
        }
    }
}

__device__ __forceinline__ void cell1_body(
    int m0, short* T,
    const unsigned short* __restrict__ h0s, const unsigned short* __restrict__ g1s,
    const float* __restrict__ h1f, const unsigned short* __restrict__ h1s,
    const short* __restrict__ Wu1T, const short* __restrict__ Wr1T,
    const short* __restrict__ Wc1T,
    const float* __restrict__ bu1, const float* __restrict__ br1,
    const float* __restrict__ bc1,
    float* __restrict__ h1nf, unsigned short* __restrict__ h1ns) {
    int lane = threadIdx.x & 63;
    int quad = lane >> 4, ln = lane & 15;
    int arow = m0 + ln; if (arow > NN - 1) arow = NN - 1;

    short8 af[6];
    af[0] = *reinterpret_cast<const short8*>(h0s + (size_t)arow * 64 + quad * 8);
    af[1] = *reinterpret_cast<const short8*>(h0s + (size_t)arow * 64 + 32 + quad * 8);
    af[2] = *reinterpret_cast<const short8*>(g1s + (size_t)arow * 64 + quad * 8);
    af[3] = *reinterpret_cast<const short8*>(g1s + (size_t)arow * 64 + 32 + quad * 8);
    af[4] = *reinterpret_cast<const short8*>(h1s + (size_t)arow * 64 + quad * 8);
    af[5] = *reinterpret_cast<const short8*>(h1s + (size_t)arow * 64 + 32 + quad * 8);

    floatx4 z = {0.f, 0.f, 0.f, 0.f};
    floatx4 aU[4] = {z, z, z, z};
    floatx4 aR[4] = {z, z, z, z};
    #pragma unroll
    for (int ct = 0; ct < 4; ++ct) {
        const short* bu = Wu1T + (size_t)(ct * 16 + ln) * 192;
        const short* br = Wr1T + (size_t)(ct * 16 + ln) * 192;
        #pragma unroll
        for (int kc = 0; kc < 6; ++kc) {
            int ko = kc * 32 + quad * 8;
            aU[ct] = MFMA(af[kc], *reinterpret_cast<const short8*>(bu + ko), aU[ct]);
            aR[ct] = MFMA(af[kc], *reinterpret_cast<const short8*>(br + ko), aR[ct]);
        }
    }
    float uu[4][4];
    #pragma unroll
    for (int ct = 0; ct < 4; ++ct) {
        int col = ct * 16 + ln;
        float bU = bu1[col], bR = br1[col];
        #pragma unroll
        for (int r = 0; r < 4; ++r) {
            int grow = m0 + quad * 4 + r;
            bool ok = grow < NN;
            uu[ct][r] = fsig(aU[ct][r] + bU);
            float hv = ok ? h1f[(size_t)grow * 64 + col] : 0.f;
            float rh = fsig(aR[ct][r] + bR) * hv;
            T[(quad * 4 + r) * 72 + col] = (short)bf16rne(rh);
        }
    }
    __threadfence_block();

    short8 ar0 = *reinterpret_cast<const short8*>(T + ln * 72 + quad * 8);
    short8 ar1 = *reinterpret_cast<const short8*>(T + ln * 72 + 32 + quad * 8);
    floatx4 aC[4] = {z, z, z, z};
    #pragma unroll
    for (int ct = 0; ct < 4; ++ct) {
        const short* bc = Wc1T + (size_t)(ct * 16 + ln) * 192;
        #pragma unroll
        for (int kc = 0; kc < 4; ++kc)
            aC[ct] = MFMA(af[kc], *reinterpret_cast<const short8*>(bc + kc * 32 + quad * 8), aC[ct]);
        aC[ct] = MFMA(ar0, *reinterpret_cast<const short8*>(bc + 128 + quad * 8), aC[ct]);
        aC[ct] = MFMA(ar1, *reinterpret_cast<const short8*>(bc + 160 + quad * 8), aC[ct]);
    }
    #pragma unroll
    for (int ct = 0; ct < 4; ++ct) {
        int col = ct * 16 + ln;
        float bC = bc1[col];
        #pragma unroll
        for (int r = 0; r < 4; ++r) {
            int grow = m0 + quad * 4 + r;
            if (grow >= NN) continue;
            float hv = h1f[(size_t)grow * 64 + col];
            float cv = ftanh(aC[ct][r] + bC);
            float hn = uu[ct][r] * hv + (1.f - uu[ct][r]) * cv;
            h1nf[(size_t)grow * 64 + col] = hn;
            h1ns[(size_t)grow * 64 + col] = bf16rne(hn);
        }
    }
}

// standalone cell0 (t=0 bootstrap)
__launch_bounds__(256, 4)
__global__ void mfma_cell0(const unsigned short* xt, const unsigned short* g0,
                           const float* h0f, const unsigned short* h0s,
                           const short* Wu0T, const short* Wr0T, const short* Wc0T, const short* Wg1T,
                           const float* bu0, const float* br0, const float* bc0,
                           float* h0nf, unsigned short* h0ns, unsigned short* y0s) {
    __shared__ short lds[4 * 16 * 72];
    int wv = threadIdx.x >> 6;
    cell0_body(blockIdx.x * 64 + wv * 16, lds + wv * (16 * 72),
               xt, g0, h0f, h0s, Wu0T, Wr0T, Wc0T, Wg1T, bu0, br0, bc0, h0nf, h0ns, y0s);
}

// merged step: blocks [0,CB) = cell1 for t; blocks [CB,2CB) = cell0 for t+1 (independent)
__launch_bounds__(256, 4)
__global__ void mfma_step(
    const unsigned short* h0s_cur, const unsigned short* g1s,
    const float* h1f_in, const unsigned short* h1s_in,
    const short* Wu1T, const short* Wr1T, const short* Wc1T,
    const float* bu1, const float* br1, const float* bc1,
    float* h1f_out, unsigned short* h1s_out,
    const unsigned short* xt_next, const unsigned short* g0_next, const float* h0f_cur,
    const short* Wu0T, const short* Wr0T, const short* Wc0T, const short* Wg1T,
    const float* bu0, const float* br0, const float* bc0,
    float* h0f_next, unsigned short* h0s_next, unsigned short* y0s) {
    __shared__ short lds[4 * 16 * 72];
    int wv = threadIdx.x >> 6;
    short* T = lds + wv * (16 * 72);
    if (blockIdx.x < CB) {
        cell1_body(blockIdx.x * 64 + wv * 16, T, h0s_cur, g1s, h1f_in, h1s_in,
                   Wu1T, Wr1T, Wc1T, bu1, br1, bc1, h1f_out, h1s_out);
    } else {
        cell0_body((blockIdx.x - CB) * 64 + wv * 16, T, xt_next, g0_next, h0f_cur, h0s_cur,
                   Wu0T, Wr0T, Wc0T, Wg1T, bu0, br0, bc0, h0f_next, h0s_next, y0s);
    }
}

// ---------------- fused qkv + attention: one wave per node ----------------
__launch_bounds__(256, 5)
__global__ void attn_fused(const unsigned short* __restrict__ hseqs,
                           const short* __restrict__ ipwB, const float* __restrict__ ipb,
                           const float* __restrict__ OW2, const float* __restrict__ ob2,
                           float* __restrict__ out) {
    __shared__ unsigned short qtile[4][16 * 200];
    __shared__ float fbuf[4][64];
    __shared__ float wbuf[4][32];
    int wv = threadIdx.x >> 6, lane = threadIdx.x & 63;
    int node = blockIdx.x * 4 + wv;
    int quad = lane >> 4, ln = lane & 15;
    unsigned short* q = qtile[wv];
    float* sob = fbuf[wv];
    float* W = wbuf[wv];

    short8 zero8 = {0, 0, 0, 0, 0, 0, 0, 0};
    short8 af0 = zero8, af1 = zero8;
    if (ln < TT) {
        const unsigned short* hp = hseqs + ((size_t)ln * NN + node) * 64;
        af0 = *reinterpret_cast<const short8*>(hp + quad * 8);
        af1 = *reinterpret_cast<const short8*>(hp + 32 + quad * 8);
    }
    floatx4 z = {0.f, 0.f, 0.f, 0.f};
    #pragma unroll
    for (int ct = 0; ct < 12; ++ct) {
        const short* br = ipwB + (size_t)(ct * 16 + ln) * 64;
        floatx4 acc = MFMA(af0, *reinterpret_cast<const short8*>(br + quad * 8), z);
        acc = MFMA(af1, *reinterpret_cast<const short8*>(br + 32 + quad * 8), acc);
        int col = ct * 16 + ln;
        float bb = ipb[col];
        #pragma unroll
        for (int r = 0; r < 4; ++r)
            q[(quad * 4 + r) * 200 + col] = bf16rne(acc[r] + bb);
    }
    __threadfence_block();

    floatx4 sc[2];
    #pragma unroll
    for (int h = 0; h < 2; ++h) {
        short8 aQ = *reinterpret_cast<const short8*>(q + ln * 200 + h * 32 + quad * 8);
        short8 bK = *reinterpret_cast<const short8*>(q + ln * 200 + 64 + h * 32 + quad * 8);
        sc[h] = MFMA(aQ, bK, z);
    }
    const float scl = 0.17677669529663687f;
    bool colok = ln < 12;
    #pragma unroll
    for (int h = 0; h < 2; ++h) {
        float p[4];
        #pragma unroll
        for (int r = 0; r < 4; ++r) {
            float v = colok ? sc[h][r] * scl : -1e30f;
            float m = v;
            m = fmaxf(m, __shfl_xor(m, 1, 64));
            m = fmaxf(m, __shfl_xor(m, 2, 64));
            m = fmaxf(m, __shfl_xor(m, 4, 64));
            m = fmaxf(m, __shfl_xor(m, 8, 64));
            float e = colok ? aexp2(LOG2E * (v - m)) : 0.f;
            float s = e;
            s += __shfl_xor(s, 1, 64);
            s += __shfl_xor(s, 2, 64);
            s += __shfl_xor(s, 4, 64);
            s += __shfl_xor(s, 8, 64);
            p[r] = e * arcp(s);
        }
        float ts = (quad < 3) ? (p[0] + p[1] + p[2] + p[3]) : 0.f;
        ts += __shfl_xor(ts, 16, 64);
        ts += __shfl_xor(ts, 32, 64);
        if (quad == 0) W[h * 16 + ln] = ts * (1.f / 12.f);
    }
    __threadfence_block();

    {
        int d = lane, hd = d >> 5, dd = d & 31;
        float acc = 0.f;
        #pragma unroll
        for (int ts = 0; ts < 12; ++ts)
            acc += W[hd * 16 + ts] * lof((unsigned)q[ts * 200 + 128 + hd * 32 + dd]);
        sob[d] = acc;
    }
    __threadfence_block();

    if (lane < OUTD) {
        float acc = ob2[lane];
        #pragma unroll
        for (int k = 0; k < 64; ++k) acc += sob[k] * OW2[k * OUTD + lane];
        out[(size_t)node * OUTD + lane] = acc;
    }
}

// ---------------- launcher ----------------

extern "C" void kernel_launch(void* const* d_in, const int* in_sizes, int n_in,
                              void* d_out, int out_size, void* d_ws, size_t ws_size,
                              hipStream_t stream) {
    const float* x   = (const float*)d_in[0];
    const int*   ei  = (const int*)d_in[1];
    const float* ea  = (const float*)d_in[2];
    const float* Wg0 = (const float*)d_in[3];
    const float* bg0 = (const float*)d_in[4];
    const float* Wu0 = (const float*)d_in[5];
    const float* bu0 = (const float*)d_in[6];
    const float* Wr0 = (const float*)d_in[7];
    const float* br0 = (const float*)d_in[8];
    const float* Wc0 = (const float*)d_in[9];
    const float* bc0 = (const float*)d_in[10];
    const float* Wg1 = (const float*)d_in[11];
    const float* bg1 = (const float*)d_in[12];
    const float* Wu1 = (const float*)d_in[13];
    const float* bu1 = (const float*)d_in[14];
    const float* Wr1 = (const float*)d_in[15];
    const float* br1 = (const float*)d_in[16];
    const float* Wc1 = (const float*)d_in[17];
    const float* bc1 = (const float*)d_in[18];
    const float* ipw = (const float*)d_in[19];
    const float* ipb = (const float*)d_in[20];
    const float* opw = (const float*)d_in[21];
    const float* opb = (const float*)d_in[22];
    const float* ow  = (const float*)d_in[23];
    const float* ob  = (const float*)d_in[24];
    float* out = (float*)d_out;

    char* p = (char*)d_ws;
    auto alloc = [&](size_t bytes) { char* r = p; p += (bytes + 255) & ~(size_t)255; return (void*)r; };
    unsigned short* hseqs = (unsigned short*)alloc((size_t)TT * NN * HH * 2);
    unsigned short* h1s0  = (unsigned short*)alloc((size_t)NN * HH * 2);
    short* Wg0T = (short*)alloc((size_t)64 * 32 * 2);
    short* Wu0T = (short*)alloc((size_t)64 * 160 * 2);
    short* Wr0T = (short*)alloc((size_t)64 * 160 * 2);
    short* Wc0T = (short*)alloc((size_t)64 * 160 * 2);
    short* Wg1T = (short*)alloc((size_t)64 * 64 * 2);
    short* Wu1T = (short*)alloc((size_t)64 * 192 * 2);
    short* Wr1T = (short*)alloc((size_t)64 * 192 * 2);
    short* Wc1T = (short*)alloc((size_t)64 * 192 * 2);
    short* ipwB = (short*)alloc((size_t)192 * 64 * 2);
    float* OW2  = (float*)alloc((size_t)64 * OUTD * 4);
    float* ob2  = (float*)alloc((size_t)OUTD * 4);
    float* dinv   = (float*)alloc((size_t)NN * 4);
    int*   rowptr = (int*)  alloc((size_t)(NN + 1) * 4);
    int2*  colval = (int2*) alloc((size_t)EE * 8);
    unsigned short* xTs   = (unsigned short*)alloc((size_t)TT * NN * FF * 2);
    unsigned short* aggxs = (unsigned short*)alloc((size_t)TT * NN * FF * 2);
    unsigned short* g0s   = (unsigned short*)alloc((size_t)TT * NN * HH * 2);
    float* deg    = (float*)alloc((size_t)NN * 4);
    int*   cnt    = (int*)  alloc((size_t)NN * 4);
    int*   cursor = (int*)  alloc((size_t)NN * 4);
    unsigned short* y0s = (unsigned short*)alloc((size_t)NN * HH * 2);
    unsigned short* g1s = (unsigned short*)alloc((size_t)NN * HH * 2);
    float* h0f0 = (float*)alloc((size_t)NN * HH * 4);
    float* h0f1 = (float*)alloc((size_t)NN * HH * 4);
    float* h1f0 = (float*)alloc((size_t)NN * HH * 4);
    float* h1f1 = (float*)alloc((size_t)NN * HH * 4);
    unsigned short* h0s0 = (unsigned short*)alloc((size_t)NN * HH * 2);
    unsigned short* h0s1 = (unsigned short*)alloc((size_t)NN * HH * 2);
    (void)ws_size;

    // fused init (replaces 5 memsets + deg_init)
    init_all<<<(NN * HH + 255) / 256, 256, 0, stream>>>(
        deg, cnt, h0f1, h1f1, (unsigned*)h0s1, (unsigned*)h1s0);
    edge_accum_kernel<<<(EE + 255) / 256, 256, 0, stream>>>(ei, ea, deg, cnt);
    scan_dinv<<<1 + (NN + 1023) / 1024, 1024, 0, stream>>>(cnt, rowptr, cursor, deg, dinv);
    fill_kernel<<<(EE + 255) / 256, 256, 0, stream>>>(ei, ea, dinv, cursor, colval);
    prep_misc<<<TRB + WCB + 4, 256, 0, stream>>>(
        x, xTs,
        Wg0, Wu0, Wr0, Wc0, Wg1, Wu1, Wr1, Wc1, ipw,
        Wg0T, Wu0T, Wr0T, Wc0T, Wg1T, Wu1T, Wr1T, Wc1T, ipwB,
        opw, opb, ow, ob, OW2, ob2);

    gather_raw32<<<dim3(NN / 16, TT), 256, 0, stream>>>(xTs, dinv, rowptr, colval, aggxs);
    mfma_g0<<<(TT * NN) / 64, 256, 0, stream>>>(aggxs, Wg0T, bg0, g0s);

    float* h0f[2] = {h0f0, h0f1};
    unsigned short* h0s[2] = {h0s0, h0s1};
    float* h1f[2] = {h1f0, h1f1};

    // C0[0]: reads zeroed buf[1], writes buf[0]
    mfma_cell0<<<CB, 256, 0, stream>>>(
        xTs, g0s, h0f[1], h0s[1], Wu0T, Wr0T, Wc0T, Wg1T, bu0, br0, bc0,
        h0f[0], h0s[0], y0s);

    for (int t = 0; t < TT; ++t) {
        gather_g1<<<NN / 8, 256, 0, stream>>>(y0s, dinv, rowptr, colval, bg1, g1s);
        int tn = (t < TT - 1) ? (t + 1) : t;   // dummy ptrs for t=11 (cell0 part not launched)
        int grid = (t < TT - 1) ? 2 * CB : CB;
        mfma_step<<<grid, 256, 0, stream>>>(
            h0s[t & 1], g1s, h1f[(t + 1) & 1],
            (t == 0) ? h1s0 : (hseqs + (size_t)(t - 1) * NN * HH),
            Wu1T, Wr1T, Wc1T, bu1, br1, bc1,
            h1f[t & 1], hseqs + (size_t)t * NN * HH,
            xTs + (size_t)tn * NN * FF, g0s + (size_t)tn * NN * HH, h0f[t & 1],
            Wu0T, Wr0T, Wc0T, Wg1T, bu0, br0, bc0,
            h0f[(t + 1) & 1], h0s[(t + 1) & 1], y0s);
    }

    attn_fused<<<NN / 4, 256, 0, stream>>>(hseqs, ipwB, ipb, OW2, ob2, out);
}